// Round 4
// baseline (108.865 us; speedup 1.0000x reference)
//
#include <hip/hip_runtime.h>

// WeatherLSTM: B=4096 indep. sequences, T=512 steps, H=10, I=O=1.
// R3 layout: 32 lanes per element = 2 gate-halves x 16 lanes.
//   half0 (lanes <32): gates i,f for hidden unit k = lane&15
//   half1 (lanes>=32): gates g,o for hidden unit k
// Uniform stream: per-lane prescaled weights + per-lane fixup constants.
// Halves exchange activations via v_permlane32_swap (VALU-rate); its register
// convention is runtime-probed once (wave-uniform) -> template<bool PICKX>.
// h all-gather: 1 ds_write_b32 + float4/float2 LDS reads (broadcast, conflict-
// free, wave-private rows -> no barrier). 2048 waves = 2 per SIMD (TLP!).

#define NLOG2E (-1.4426950408889634f)

template<bool PICKX>
__device__ __forceinline__ float pickf(unsigned x, unsigned y) {
    return __uint_as_float(PICKX ? x : y);
}

template<bool PICKX>
__device__ __forceinline__ void lstm_run(
    const float* __restrict__ xe, int T,
    const float (&wh)[2][10], float wi0, float wi1, float bb0, float bb1,
    float fm, float fa, float* hrow, float (&h)[10])
{
    const int k = threadIdx.x & 15;
    #pragma unroll
    for (int j = 0; j < 10; ++j) h[j] = 0.0f;
    float c = 0.0f;

    float4 xv = *reinterpret_cast<const float4*>(xe);
    for (int s0 = 0; s0 < T; s0 += 4) {
        const int snext = (s0 + 4 < T) ? (s0 + 4) : s0;   // clamped prefetch
        const float4 xnext = *reinterpret_cast<const float4*>(xe + snext);
        #pragma unroll
        for (int ss = 0; ss < 4; ++ss) {
            const float xt = (&xv.x)[ss];

            // two gate dot products (prescaled: result is the exp2 argument)
            float aA0 = fmaf(xt, wi0, bb0);
            float aA1 = fmaf(xt, wi1, bb1);
            float aB0 = h[5] * wh[0][5];
            float aB1 = h[5] * wh[1][5];
            #pragma unroll
            for (int j = 0; j < 5; ++j) {
                aA0 = fmaf(h[j], wh[0][j], aA0);
                aA1 = fmaf(h[j], wh[1][j], aA1);
            }
            #pragma unroll
            for (int j = 6; j < 10; ++j) {
                aB0 = fmaf(h[j], wh[0][j], aB0);
                aB1 = fmaf(h[j], wh[1][j], aB1);
            }
            const float r0 = __builtin_amdgcn_rcpf(
                1.0f + __builtin_amdgcn_exp2f(aA0 + aB0));
            const float r1 = __builtin_amdgcn_rcpf(
                1.0f + __builtin_amdgcn_exp2f(aA1 + aB1));
            const float a0 = fmaf(fm, r0, fa);   // tanh fixup on g-gate lanes
            const float a1 = r1;

            // exchange with partner half (lane ^ 32); both outputs usable:
            // {x,y} = {value-from-lo-owner bcast, value-from-hi-owner bcast}
            auto w0 = __builtin_amdgcn_permlane32_swap(
                __float_as_uint(a0), __float_as_uint(a0), false, false);
            auto w1 = __builtin_amdgcn_permlane32_swap(
                __float_as_uint(a1), __float_as_uint(a1), false, false);
            const float iv = pickf<PICKX>(w0[0], w0[1]);  // i (from half0 a0)
            const float gv = pickf<PICKX>(w0[1], w0[0]);  // g (from half1 a0)
            const float fv = pickf<PICKX>(w1[0], w1[1]);  // f (from half0 a1)
            const float ov = pickf<PICKX>(w1[1], w1[0]);  // o (from half1 a1)

            // c/h maintained redundantly (bit-identical) in all 32 lanes
            c = fmaf(fv, c, iv * gv);
            const float e2 = __builtin_amdgcn_exp2f(c * (2.0f * NLOG2E));
            const float th = fmaf(2.0f, __builtin_amdgcn_rcpf(1.0f + e2), -1.0f);
            const float hown = ov * th;

            // h all-gather via wave-private LDS row (in-order DS pipe, no bar)
            hrow[k] = hown;
            const float4 h03 = *reinterpret_cast<const float4*>(hrow);
            const float4 h47 = *reinterpret_cast<const float4*>(hrow + 4);
            const float2 h89 = *reinterpret_cast<const float2*>(hrow + 8);
            h[0] = h03.x; h[1] = h03.y; h[2] = h03.z; h[3] = h03.w;
            h[4] = h47.x; h[5] = h47.y; h[6] = h47.z; h[7] = h47.w;
            h[8] = h89.x; h[9] = h89.y;
        }
        xv = xnext;
    }
}

__global__ __launch_bounds__(256, 2) void WeatherLSTM_kernel(
    const float* __restrict__ x,     // [B, T, 1]
    const float* __restrict__ W_ih,  // [40, 1]
    const float* __restrict__ W_hh,  // [40, 10]
    const float* __restrict__ b_ih,  // [40]
    const float* __restrict__ b_hh,  // [40]
    const float* __restrict__ W_fc,  // [1, 10]
    const float* __restrict__ b_fc,  // [1]
    float* __restrict__ out,         // [B, 1]
    int T)
{
    __shared__ float hsh[8][16];     // 8 elems/block, wave-private rows
    const int tid  = threadIdx.x;
    const int lane = tid & 63;
    const int wav  = tid >> 6;
    const int k    = lane & 15;      // hidden unit; active iff k < 10
    const int h1   = lane >> 5;      // gate half: 0 -> (i,f), 1 -> (g,o)
    const int eib  = wav * 2 + ((lane >> 4) & 1);
    const long e   = (long)blockIdx.x * 8 + eib;
    const bool act = (k < 10);

    // Own 2 gate rows, prescaled by the activation's exp2 factor:
    // sigmoid(v)=rcp(1+exp2(-v*log2e)); tanh(v)=2*rcp(1+exp2(-2v*log2e))-1
    float wh[2][10], wiv[2], bbv[2];
    #pragma unroll
    for (int p = 0; p < 2; ++p) {
        const int t = 2 * h1 + p;                       // gate index i,f,g,o
        const float s = (t == 2) ? (2.0f * NLOG2E) : NLOG2E;
        const int g = t * 10 + k;
        wiv[p] = act ? W_ih[g] * s : 0.0f;
        bbv[p] = act ? (b_ih[g] + b_hh[g]) * s : 0.0f;
        #pragma unroll
        for (int j = 0; j < 10; ++j)
            wh[p][j] = act ? W_hh[g * 10 + j] * s : 0.0f;
    }
    const float fm = h1 ? 2.0f : 1.0f;    // tanh fixup for gate g (t==2)
    const float fa = h1 ? -1.0f : 0.0f;

    // Probe permlane32_swap register convention once (wave-uniform result)
    auto pr = __builtin_amdgcn_permlane32_swap((unsigned)lane, (unsigned)lane,
                                               false, false);
    const bool pickx = ((int)pr[0] == (lane & 31));

    float h[10];
    if (pickx)
        lstm_run<true >(x + e * (long)T, T, wh, wiv[0], wiv[1], bbv[0], bbv[1],
                        fm, fa, &hsh[eib][0], h);
    else
        lstm_run<false>(x + e * (long)T, T, wh, wiv[0], wiv[1], bbv[0], bbv[1],
                        fm, fa, &hsh[eib][0], h);

    if (k == 0 && h1 == 0) {
        float o = b_fc[0];
        #pragma unroll
        for (int j = 0; j < 10; ++j)
            o = fmaf(h[j], W_fc[j], o);
        out[e] = o;
    }
}

extern "C" void kernel_launch(void* const* d_in, const int* in_sizes, int n_in,
                              void* d_out, int out_size, void* d_ws, size_t ws_size,
                              hipStream_t stream) {
    const float* x    = (const float*)d_in[0];
    const float* W_ih = (const float*)d_in[1];
    const float* W_hh = (const float*)d_in[2];
    const float* b_ih = (const float*)d_in[3];
    const float* b_hh = (const float*)d_in[4];
    const float* W_fc = (const float*)d_in[5];
    const float* b_fc = (const float*)d_in[6];
    float* out = (float*)d_out;

    const int B = out_size;          // 4096
    const int T = in_sizes[0] / B;   // 512

    dim3 grid(B / 8), block(256);    // 8 elems/block, 512 blocks, 2 waves/SIMD
    hipLaunchKernelGGL(WeatherLSTM_kernel, grid, block, 0, stream,
                       x, W_ih, W_hh, b_ih, b_hh, W_fc, b_fc, out, T);
}